// Round 4
// baseline (105.511 us; speedup 1.0000x reference)
//
#include <hip/hip_runtime.h>
#include <math.h>

#define L      2048
#define DDIM   512
#define NBATCH 8
#define BM     256            // j-rows per block
#define BN     128            // k-cols per block
#define BK     32             // K-tile (of augmented K = 1536)
#define KAUG   (3 * DDIM)     // 1536
#define NKT    (KAUG / BK)    // 48 K-tiles
#define NJT    (L / BM)       // 8
#define NKTIL  (L / BN)       // 16
#define PAIRS_PER_BATCH 72    // sum_{tj} (16 - 2*tj)
#define TOTAL_BLOCKS (NBATCH * PAIRS_PER_BATCH)  // 576

#define ALPHA  0.1f
#define BETA   0.3f
#define MARGIN 2.0f

typedef __attribute__((ext_vector_type(8))) short bf16x8;
typedef __attribute__((ext_vector_type(4))) float f32x4;

#define GLOAD_LDS16(g, l) __builtin_amdgcn_global_load_lds(              \
    (const __attribute__((address_space(1))) unsigned int*)(g),          \
    (__attribute__((address_space(3))) unsigned int*)(l), 16, 0, 0)

__device__ __forceinline__ unsigned short f2bf_rne(float x) {
    unsigned u = __float_as_uint(x);
    unsigned r = (u + 0x7FFFu + ((u >> 16) & 1u)) >> 16;
    return (unsigned short)r;
}
__device__ __forceinline__ float bf2f(unsigned short h) {
    return __uint_as_float(((unsigned)h) << 16);
}

// ---------------------------------------------------------------------------
// Kernel 1: fp32 -> (hi, lo) bf16 split + per-row squared norms (exact fp32).
// ---------------------------------------------------------------------------
__global__ __launch_bounds__(256) void conv_kernel(const float* __restrict__ pred,
                                                   unsigned short* __restrict__ hi,
                                                   unsigned short* __restrict__ lo,
                                                   float* __restrict__ sq) {
    int w    = threadIdx.x >> 6;
    int lane = threadIdx.x & 63;
    int row  = blockIdx.x * 4 + w;
    const float* p = pred + (size_t)row * DDIM + lane * 8;
    float4 v0 = *(const float4*)(p);
    float4 v1 = *(const float4*)(p + 4);
    float vals[8] = {v0.x, v0.y, v0.z, v0.w, v1.x, v1.y, v1.z, v1.w};
    unsigned short hb[8], lb[8];
    float s = 0.0f;
    #pragma unroll
    for (int i = 0; i < 8; ++i) {
        float x = vals[i];
        s = fmaf(x, x, s);
        unsigned short h = f2bf_rne(x);
        float rem = x - bf2f(h);
        hb[i] = h;
        lb[i] = f2bf_rne(rem);
    }
    size_t o = (size_t)row * DDIM + lane * 8;
    *(ushort4*)(hi + o)     = make_ushort4(hb[0], hb[1], hb[2], hb[3]);
    *(ushort4*)(hi + o + 4) = make_ushort4(hb[4], hb[5], hb[6], hb[7]);
    *(ushort4*)(lo + o)     = make_ushort4(lb[0], lb[1], lb[2], lb[3]);
    *(ushort4*)(lo + o + 4) = make_ushort4(lb[4], lb[5], lb[6], lb[7]);
    #pragma unroll
    for (int off = 32; off > 0; off >>= 1) s += __shfl_down(s, off);
    if (lane == 0) sq[row] = s;
}

// ---------------------------------------------------------------------------
// Kernel 2: augmented-K GEMM (K=1536: A-src {hi,lo,hi}, B-src {hi,hi,lo} per
// 512-segment => hi.hi + lo.hi + hi.lo) + fused loss + per-block reduction.
// BM=256 x BN=128, 8 waves (4x2, per-wave 64x64), BK=32.
// Double-buffered 48KB LDS, depth-1 prefetch with COUNTED vmcnt(3) (never 0
// in-loop), raw s_barrier, setprio around MFMA cluster.
// LDS chunk-swizzle: chunk ^= (row>>1)&3 applied on stage-SOURCE and ds_read.
// Per-element weights {2,1,0} implement j<=k symmetry at any tile shape.
// ---------------------------------------------------------------------------
__global__ __launch_bounds__(512, 4) void loss_kernel(
        const unsigned short* __restrict__ hi,
        const unsigned short* __restrict__ lo,
        const int*   __restrict__ seg,
        const float* __restrict__ sq,
        double*      __restrict__ partials) {
    // buffer: [A: 256*32][B: 128*32] shorts = 12288 shorts = 24KB; x2 = 48KB
    __shared__ unsigned short smem[2 * (BM * BK + BN * BK)];
    const int ABUF = BM * BK;            // 8192 shorts
    const int BUFS = BM * BK + BN * BK;  // 12288 shorts

    int bid = blockIdx.x;
    int n = bid & 7;            // batch -> XCD round-robin
    int p = bid >> 3;           // 0..71
    int tj = 0, width = NKTIL;  // widths 16,14,12,...
    while (p >= width) { p -= width; ++tj; width -= 2; }
    int tk = 2 * tj + p;
    int j0 = tj * BM, k0 = tk * BN;

    int t    = threadIdx.x;
    int w    = t >> 6;          // 0..7
    int lane = t & 63;
    int wr   = w >> 1;          // 0..3 : 64-row band
    int wc   = w & 1;           // 0..1 : 64-col band

    const unsigned short* baseHi = hi + (size_t)n * L * DDIM;
    const unsigned short* baseLo = lo + (size_t)n * L * DDIM;

    // staging geometry: one gload_lds writes 1KB = 16 rows x 64B.
    int rl = lane >> 2;          // 0..15 row within 16-row group
    int cc = lane & 3;           // dest 16B-chunk within 64B row
    int instA0 = w * 2;          // A instances w*2, w*2+1 (rows inst*16..)
    int instB  = w;              // B instance w

    f32x4 acc[4][4];
    #pragma unroll
    for (int m = 0; m < 4; ++m)
        #pragma unroll
        for (int nn = 0; nn < 4; ++nn) acc[m][nn] = (f32x4){0.f, 0.f, 0.f, 0.f};

    int lrow = lane & 15;
    int lq   = lane >> 4;        // 0..3 (also the logical k-chunk for frags)

    // ---- staging helper (issues 3 gload_lds for K-tile kt into buf b) ----
    #define STAGE(kt, b)                                                      \
    {                                                                         \
        int _s  = (kt) >> 4;                                                  \
        int _c0 = ((kt) & 15) * BK;                                           \
        const unsigned short* _sa = (_s == 1) ? baseLo : baseHi;              \
        const unsigned short* _sb = (_s == 2) ? baseLo : baseHi;              \
        unsigned short* _dst = smem + (b) * BUFS;                             \
        _Pragma("unroll")                                                     \
        for (int q = 0; q < 2; ++q) {                                         \
            int inst = instA0 + q;                                            \
            int r    = inst * 16 + rl;                                        \
            int sc   = cc ^ ((r >> 1) & 3);                                   \
            GLOAD_LDS16(_sa + (size_t)(j0 + r) * DDIM + _c0 + sc * 8,         \
                        _dst + inst * 512);                                   \
        }                                                                     \
        {                                                                     \
            int r  = instB * 16 + rl;                                         \
            int sc = cc ^ ((r >> 1) & 3);                                     \
            GLOAD_LDS16(_sb + (size_t)(k0 + r) * DDIM + _c0 + sc * 8,         \
                        _dst + ABUF + instB * 512);                           \
        }                                                                     \
    }

    STAGE(0, 0);   // prologue: tile 0 -> buf 0

    #pragma unroll 2
    for (int kt = 0; kt < NKT; ++kt) {
        int cur = kt & 1;
        __builtin_amdgcn_s_barrier();            // all waves done reading buf[cur^1]
        if (kt + 1 < NKT) STAGE(kt + 1, cur ^ 1); // prefetch next tile (3 loads)
        asm volatile("s_waitcnt vmcnt(3)" ::: "memory");  // tile kt resident (wave-local)
        __builtin_amdgcn_s_barrier();            // ... and for all waves
        asm volatile("" ::: "memory");

        const unsigned short* A = smem + cur * BUFS;
        const unsigned short* B = A + ABUF;

        bf16x8 af[4], bf[4];
        #pragma unroll
        for (int m = 0; m < 4; ++m) {
            int R = wr * 64 + m * 16 + lrow;
            af[m] = *(const bf16x8*)&A[R * 32 + ((lq ^ ((R >> 1) & 3)) << 3)];
        }
        #pragma unroll
        for (int nn = 0; nn < 4; ++nn) {
            int R = wc * 64 + nn * 16 + lrow;
            bf[nn] = *(const bf16x8*)&B[R * 32 + ((lq ^ ((R >> 1) & 3)) << 3)];
        }
        __builtin_amdgcn_s_setprio(1);
        #pragma unroll
        for (int m = 0; m < 4; ++m)
            #pragma unroll
            for (int nn = 0; nn < 4; ++nn)
                acc[m][nn] = __builtin_amdgcn_mfma_f32_16x16x32_bf16(
                    af[m], bf[nn], acc[m][nn], 0, 0, 0);
        __builtin_amdgcn_s_setprio(0);
    }

    // ------------------- fused loss epilogue -------------------
    // C/D layout: col = lane&15 (k), row = lq*4 + reg (j)
    const int*   segb = seg + n * L;
    const float* sqb  = sq + n * L;

    float sqk[4]; int sgk[4];
    #pragma unroll
    for (int nn = 0; nn < 4; ++nn) {
        int k = k0 + wc * 64 + nn * 16 + lrow;
        sqk[nn] = sqb[k]; sgk[nn] = segb[k];
    }
    float sqj[4][4]; int sgj[4][4];
    #pragma unroll
    for (int m = 0; m < 4; ++m)
        #pragma unroll
        for (int reg = 0; reg < 4; ++reg) {
            int j = j0 + wr * 64 + m * 16 + lq * 4 + reg;
            sqj[m][reg] = sqb[j]; sgj[m][reg] = segb[j];
        }

    float lsum = 0.0f;   // weighted: 2*(j<k) + 1*(j==k)
    #pragma unroll
    for (int m = 0; m < 4; ++m)
        #pragma unroll
        for (int nn = 0; nn < 4; ++nn)
            #pragma unroll
            for (int reg = 0; reg < 4; ++reg) {
                int jg = j0 + wr * 64 + m * 16 + lq * 4 + reg;
                int kg = k0 + wc * 64 + nn * 16 + lrow;
                if (jg > kg) continue;
                float inner = acc[m][nn][reg];
                float d2 = fmaxf(sqj[m][reg] + sqk[nn] - 2.0f * inner, 0.0f);
                float v;
                if (sgj[m][reg] == sgk[nn]) {
                    v = ALPHA * d2;
                } else {
                    float dist = sqrtf(d2);
                    float h = fmaxf(MARGIN - dist, 0.0f);
                    v = BETA * h * h;
                }
                lsum += (jg < kg) ? 2.0f * v : v;
            }

    __syncthreads();                       // done with LDS tiles (drains all)
    double* red = (double*)smem;           // alias reduction onto tile LDS
    red[t] = (double)lsum;
    __syncthreads();
    #pragma unroll
    for (int s = 256; s > 0; s >>= 1) {
        if (t < s) red[t] += red[t + s];
        __syncthreads();
    }
    if (t == 0) partials[blockIdx.x] = red[0];
}

// ---------------------------------------------------------------------------
// Kernel 3: deterministic final reduction -> mean.
// ---------------------------------------------------------------------------
__global__ __launch_bounds__(256) void reduce_kernel(const double* __restrict__ partials,
                                                     float* __restrict__ out,
                                                     int nPart, double invCount) {
    __shared__ double red[256];
    int t = threadIdx.x;
    double s = 0.0;
    for (int i = t; i < nPart; i += 256) s += partials[i];
    red[t] = s;
    __syncthreads();
    #pragma unroll
    for (int k = 128; k > 0; k >>= 1) {
        if (t < k) red[t] += red[t + k];
        __syncthreads();
    }
    if (t == 0) out[0] = (float)(red[0] * invCount);
}

extern "C" void kernel_launch(void* const* d_in, const int* in_sizes, int n_in,
                              void* d_out, int out_size, void* d_ws, size_t ws_size,
                              hipStream_t stream) {
    const float* pred = (const float*)d_in[0];
    const int*   seg  = (const int*)d_in[1];
    float* out = (float*)d_out;

    const size_t HALF = (size_t)NBATCH * L * DDIM;
    unsigned short* hi = (unsigned short*)d_ws;
    unsigned short* lo = hi + HALF;
    float*  sq         = (float*)(lo + HALF);
    double* partials   = (double*)(sq + NBATCH * L);

    conv_kernel<<<NBATCH * L / 4, 256, 0, stream>>>(pred, hi, lo, sq);
    loss_kernel<<<TOTAL_BLOCKS, 512, 0, stream>>>(hi, lo, seg, sq, partials);
    reduce_kernel<<<1, 256, 0, stream>>>(partials, out, TOTAL_BLOCKS,
                                         1.0 / (double)((size_t)NBATCH * L * L));
}

// Round 5
// 105.204 us; speedup vs baseline: 1.0029x; 1.0029x over previous
//
#include <hip/hip_runtime.h>
#include <math.h>

#define L      2048
#define DDIM   512
#define NBATCH 8
#define BM     128
#define BN     128
#define BK     32
#define NKT    (DDIM / BK)               // 16 K-tiles
#define NTILE  (L / BM)                  // 16
#define NPAIR  (NTILE * (NTILE + 1) / 2) // 136
#define TOTAL_BLOCKS (NBATCH * NPAIR)    // 1088

#define ALPHA  0.1f
#define BETA   0.3f
#define MARGIN 2.0f

typedef __attribute__((ext_vector_type(8)))  short bf16x8;
typedef __attribute__((ext_vector_type(16))) float f32x16;

// tile offsets in shorts within one 32KB buffer
#define TA_HI 0
#define TA_LO 4096
#define TB_HI 8192
#define TB_LO 12288
#define BUFS  16384    // shorts per buffer (32 KB)

#define GLOAD_LDS16(g, l) __builtin_amdgcn_global_load_lds(              \
    (const __attribute__((address_space(1))) unsigned int*)(g),          \
    (__attribute__((address_space(3))) unsigned int*)(l), 16, 0, 0)

__device__ __forceinline__ unsigned short f2bf_rne(float x) {
    unsigned u = __float_as_uint(x);
    unsigned r = (u + 0x7FFFu + ((u >> 16) & 1u)) >> 16;
    return (unsigned short)r;
}
__device__ __forceinline__ float bf2f(unsigned short h) {
    return __uint_as_float(((unsigned)h) << 16);
}

// ---------------------------------------------------------------------------
// Kernel 1: fp32 -> (hi, lo) bf16 split + per-row squared norms (exact fp32).
// ---------------------------------------------------------------------------
__global__ __launch_bounds__(256) void conv_kernel(const float* __restrict__ pred,
                                                   unsigned short* __restrict__ hi,
                                                   unsigned short* __restrict__ lo,
                                                   float* __restrict__ sq) {
    int w    = threadIdx.x >> 6;
    int lane = threadIdx.x & 63;
    int row  = blockIdx.x * 4 + w;
    const float* p = pred + (size_t)row * DDIM + lane * 8;
    float4 v0 = *(const float4*)(p);
    float4 v1 = *(const float4*)(p + 4);
    float vals[8] = {v0.x, v0.y, v0.z, v0.w, v1.x, v1.y, v1.z, v1.w};
    unsigned short hb[8], lb[8];
    float s = 0.0f;
    #pragma unroll
    for (int i = 0; i < 8; ++i) {
        float x = vals[i];
        s = fmaf(x, x, s);
        unsigned short h = f2bf_rne(x);
        float rem = x - bf2f(h);
        hb[i] = h;
        lb[i] = f2bf_rne(rem);
    }
    size_t o = (size_t)row * DDIM + lane * 8;
    *(ushort4*)(hi + o)     = make_ushort4(hb[0], hb[1], hb[2], hb[3]);
    *(ushort4*)(hi + o + 4) = make_ushort4(hb[4], hb[5], hb[6], hb[7]);
    *(ushort4*)(lo + o)     = make_ushort4(lb[0], lb[1], lb[2], lb[3]);
    *(ushort4*)(lo + o + 4) = make_ushort4(lb[4], lb[5], lb[6], lb[7]);
    #pragma unroll
    for (int off = 32; off > 0; off >>= 1) s += __shfl_down(s, off);
    if (lane == 0) sq[row] = s;
}

// ---------------------------------------------------------------------------
// Kernel 2: merged split-bf16 GEMM (Hi*Hi + Hi*Lo + Lo*Hi per K-tile) with
// mfma_f32_32x32x16_bf16, fused loss, per-block reduction.
// 128x128 tile, 4 waves (2x2 of 64x64, each 2x2 frags of 32x32).
// BK=32, 4 tiles/buffer (32KB), DOUBLE-buffered (64KB) -> 2 blocks/CU.
// Pipeline: barrier; STAGE(kt+1) [8 gload_lds]; s_waitcnt vmcnt(8) (counted,
// never 0 in-loop); barrier; ds_read+MFMA. Loads stay in flight across
// barriers (T3/T4). Chunk-swizzle (chunk ^= row&3) on stage-source + read.
// ---------------------------------------------------------------------------
__global__ __launch_bounds__(256) void loss_kernel(
        const unsigned short* __restrict__ hi,
        const unsigned short* __restrict__ lo,
        const int*   __restrict__ seg,
        const float* __restrict__ sq,
        double*      __restrict__ partials) {
    __shared__ unsigned short smem[2 * BUFS];   // 64 KB

    int bid = blockIdx.x;
    int n = bid & 7;            // batch -> XCD round-robin
    int p = bid >> 3;           // 0..135
    int tj = 0;
    while (true) {
        int rl2 = NTILE - tj;
        if (p < rl2) break;
        p -= rl2;
        ++tj;
    }
    int tk = tj + p;
    int j0 = tj * BM, k0 = tk * BN;

    int t    = threadIdx.x;
    int w    = t >> 6;          // 0..3
    int lane = t & 63;
    int wr   = w >> 1, wc = w & 1;     // 64x64 quadrant
    int l31  = lane & 31;
    int hsel = lane >> 5;              // 0/1: k-halfslice of the frag

    const unsigned short* baseHi = hi + (size_t)n * L * DDIM;
    const unsigned short* baseLo = lo + (size_t)n * L * DDIM;

    // staging geometry: tile 128x32 (8KB) = 8 insts x 1KB (16 rows x 64B).
    // wave w does insts {2w, 2w+1} of each tile: 8 gload_lds per thread.
    int rl = lane >> 2;          // row within 16-row inst group
    int cc = lane & 3;           // dest 16B chunk within 64B row

    f32x16 acc[2][2];
    #pragma unroll
    for (int m = 0; m < 2; ++m)
        #pragma unroll
        for (int nn = 0; nn < 2; ++nn)
            #pragma unroll
            for (int r = 0; r < 16; ++r) acc[m][nn][r] = 0.0f;

    #define STAGE(kt, b)                                                      \
    {                                                                         \
        int _c0 = (kt) * BK;                                                  \
        unsigned short* _dst = smem + (b) * BUFS;                             \
        _Pragma("unroll")                                                     \
        for (int q = 0; q < 2; ++q) {                                         \
            int inst = w * 2 + q;                                             \
            int r    = inst * 16 + rl;                                        \
            int sc   = (cc ^ (r & 3)) << 3;                                   \
            size_t ga = (size_t)(j0 + r) * DDIM + _c0 + sc;                   \
            size_t gb = (size_t)(k0 + r) * DDIM + _c0 + sc;                   \
            GLOAD_LDS16(baseHi + ga, _dst + TA_HI + inst * 512);              \
            GLOAD_LDS16(baseLo + ga, _dst + TA_LO + inst * 512);              \
            GLOAD_LDS16(baseHi + gb, _dst + TB_HI + inst * 512);              \
            GLOAD_LDS16(baseLo + gb, _dst + TB_LO + inst * 512);              \
        }                                                                     \
    }

    STAGE(0, 0);   // prologue

    #pragma unroll 2
    for (int kt = 0; kt < NKT; ++kt) {
        int cur = kt & 1;
        __builtin_amdgcn_s_barrier();          // all waves done reading buf[cur^1]
        if (kt + 1 < NKT) {
            STAGE(kt + 1, cur ^ 1);
            asm volatile("s_waitcnt vmcnt(8)" ::: "memory");  // tile kt resident
        } else {
            asm volatile("s_waitcnt vmcnt(0)" ::: "memory");
        }
        __builtin_amdgcn_s_barrier();          // tile kt visible to all waves

        const unsigned short* B0 = smem + cur * BUFS;

        #pragma unroll
        for (int ks = 0; ks < 2; ++ks) {       // two K=16 steps
            int kc = ks * 2 + hsel;            // logical 8-elem chunk 0..3
            bf16x8 ah[2], al[2], bh[2], bl[2];
            #pragma unroll
            for (int m = 0; m < 2; ++m) {
                int R   = wr * 64 + m * 32 + l31;
                int off = R * 32 + ((kc ^ (R & 3)) << 3);
                ah[m] = *(const bf16x8*)&B0[TA_HI + off];
                al[m] = *(const bf16x8*)&B0[TA_LO + off];
            }
            #pragma unroll
            for (int nn = 0; nn < 2; ++nn) {
                int R   = wc * 64 + nn * 32 + l31;
                int off = R * 32 + ((kc ^ (R & 3)) << 3);
                bh[nn] = *(const bf16x8*)&B0[TB_HI + off];
                bl[nn] = *(const bf16x8*)&B0[TB_LO + off];
            }
            __builtin_amdgcn_s_setprio(1);
            #pragma unroll
            for (int m = 0; m < 2; ++m)
                #pragma unroll
                for (int nn = 0; nn < 2; ++nn) {
                    acc[m][nn] = __builtin_amdgcn_mfma_f32_32x32x16_bf16(
                        ah[m], bh[nn], acc[m][nn], 0, 0, 0);
                    acc[m][nn] = __builtin_amdgcn_mfma_f32_32x32x16_bf16(
                        ah[m], bl[nn], acc[m][nn], 0, 0, 0);
                    acc[m][nn] = __builtin_amdgcn_mfma_f32_32x32x16_bf16(
                        al[m], bh[nn], acc[m][nn], 0, 0, 0);
                }
            __builtin_amdgcn_s_setprio(0);
        }
    }

    // ------------------- fused loss epilogue -------------------
    // 32x32 C/D layout: col = lane&31, row = (reg&3) + 8*(reg>>2) + 4*(lane>>5)
    const int*   segb = seg + n * L;
    const float* sqb  = sq + n * L;

    float sqk[2]; int sgk[2];
    #pragma unroll
    for (int nn = 0; nn < 2; ++nn) {
        int k = k0 + wc * 64 + nn * 32 + l31;
        sqk[nn] = sqb[k]; sgk[nn] = segb[k];
    }
    float sqj[2][16]; int sgj[2][16];
    #pragma unroll
    for (int m = 0; m < 2; ++m)
        #pragma unroll
        for (int r = 0; r < 16; ++r) {
            int j = j0 + wr * 64 + m * 32 + (r & 3) + 8 * (r >> 2) + 4 * hsel;
            sqj[m][r] = sqb[j]; sgj[m][r] = segb[j];
        }

    float lsum = 0.0f;
    #pragma unroll
    for (int m = 0; m < 2; ++m)
        #pragma unroll
        for (int nn = 0; nn < 2; ++nn)
            #pragma unroll
            for (int r = 0; r < 16; ++r) {
                float inner = acc[m][nn][r];
                float d2 = fmaxf(sqj[m][r] + sqk[nn] - 2.0f * inner, 0.0f);
                float v;
                if (sgj[m][r] == sgk[nn]) {
                    v = ALPHA * d2;
                } else {
                    float dist = sqrtf(d2);
                    float h = fmaxf(MARGIN - dist, 0.0f);
                    v = BETA * h * h;
                }
                lsum += v;
            }

    double wgt = (tj == tk) ? 1.0 : 2.0;
    __syncthreads();                       // done with LDS tiles
    double* red = (double*)smem;
    red[t] = (double)lsum * wgt;
    __syncthreads();
    #pragma unroll
    for (int s = 128; s > 0; s >>= 1) {
        if (t < s) red[t] += red[t + s];
        __syncthreads();
    }
    if (t == 0) partials[blockIdx.x] = red[0];
}

// ---------------------------------------------------------------------------
// Kernel 3: deterministic final reduction -> mean.
// ---------------------------------------------------------------------------
__global__ __launch_bounds__(256) void reduce_kernel(const double* __restrict__ partials,
                                                     float* __restrict__ out,
                                                     int nPart, double invCount) {
    __shared__ double red[256];
    int t = threadIdx.x;
    double s = 0.0;
    for (int i = t; i < nPart; i += 256) s += partials[i];
    red[t] = s;
    __syncthreads();
    #pragma unroll
    for (int k = 128; k > 0; k >>= 1) {
        if (t < k) red[t] += red[t + k];
        __syncthreads();
    }
    if (t == 0) out[0] = (float)(red[0] * invCount);
}

extern "C" void kernel_launch(void* const* d_in, const int* in_sizes, int n_in,
                              void* d_out, int out_size, void* d_ws, size_t ws_size,
                              hipStream_t stream) {
    const float* pred = (const float*)d_in[0];
    const int*   seg  = (const int*)d_in[1];
    float* out = (float*)d_out;

    const size_t HALF = (size_t)NBATCH * L * DDIM;
    unsigned short* hi = (unsigned short*)d_ws;
    unsigned short* lo = hi + HALF;
    float*  sq         = (float*)(lo + HALF);
    double* partials   = (double*)(sq + NBATCH * L);

    conv_kernel<<<NBATCH * L / 4, 256, 0, stream>>>(pred, hi, lo, sq);
    loss_kernel<<<TOTAL_BLOCKS, 256, 0, stream>>>(hi, lo, seg, sq, partials);
    reduce_kernel<<<1, 256, 0, stream>>>(partials, out, TOTAL_BLOCKS,
                                         1.0 / (double)((size_t)NBATCH * L * L));
}

// Round 6
// 96.344 us; speedup vs baseline: 1.0951x; 1.0920x over previous
//
#include <hip/hip_runtime.h>
#include <math.h>

#define L      2048
#define DDIM   512
#define NBATCH 8
#define BM     128
#define BN     128
#define BK     32
#define NKT    (DDIM / BK)               // 16 K-tiles
#define NTILE  (L / BM)                  // 16
#define NPAIR  (NTILE * (NTILE + 1) / 2) // 136
#define TOTAL_BLOCKS (NBATCH * NPAIR)    // 1088

#define ALPHA  0.1f
#define BETA   0.3f
#define MARGIN 2.0f

typedef __attribute__((ext_vector_type(8)))  short bf16x8;
typedef __attribute__((ext_vector_type(16))) float f32x16;

// One buffer: A tile [128 rows x 128B] then B tile [128 rows x 128B].
// Row layout: 8 chunks of 8 shorts; logical chunk 0..3 = hi k-chunks,
// 4..7 = lo k-chunks; physical chunk = logical ^ (row & 7)  (bank swizzle).
#define TILE_SH 8192              // shorts per tile (16 KB)
#define BUFS    16384             // shorts per buffer (32 KB)

#define GLOAD_LDS16(g, l) __builtin_amdgcn_global_load_lds(              \
    (const __attribute__((address_space(1))) unsigned int*)(g),          \
    (__attribute__((address_space(3))) unsigned int*)(l), 16, 0, 0)

__device__ __forceinline__ unsigned short f2bf_rne(float x) {
    unsigned u = __float_as_uint(x);
    unsigned r = (u + 0x7FFFu + ((u >> 16) & 1u)) >> 16;
    return (unsigned short)r;
}
__device__ __forceinline__ float bf2f(unsigned short h) {
    return __uint_as_float(((unsigned)h) << 16);
}

// ---------------------------------------------------------------------------
// Kernel 1: fp32 -> (hi, lo) bf16 split + per-row squared norms (exact fp32).
// ---------------------------------------------------------------------------
__global__ __launch_bounds__(256) void conv_kernel(const float* __restrict__ pred,
                                                   unsigned short* __restrict__ hi,
                                                   unsigned short* __restrict__ lo,
                                                   float* __restrict__ sq) {
    int w    = threadIdx.x >> 6;
    int lane = threadIdx.x & 63;
    int row  = blockIdx.x * 4 + w;
    const float* p = pred + (size_t)row * DDIM + lane * 8;
    float4 v0 = *(const float4*)(p);
    float4 v1 = *(const float4*)(p + 4);
    float vals[8] = {v0.x, v0.y, v0.z, v0.w, v1.x, v1.y, v1.z, v1.w};
    unsigned short hb[8], lb[8];
    float s = 0.0f;
    #pragma unroll
    for (int i = 0; i < 8; ++i) {
        float x = vals[i];
        s = fmaf(x, x, s);
        unsigned short h = f2bf_rne(x);
        float rem = x - bf2f(h);
        hb[i] = h;
        lb[i] = f2bf_rne(rem);
    }
    size_t o = (size_t)row * DDIM + lane * 8;
    *(ushort4*)(hi + o)     = make_ushort4(hb[0], hb[1], hb[2], hb[3]);
    *(ushort4*)(hi + o + 4) = make_ushort4(hb[4], hb[5], hb[6], hb[7]);
    *(ushort4*)(lo + o)     = make_ushort4(lb[0], lb[1], lb[2], lb[3]);
    *(ushort4*)(lo + o + 4) = make_ushort4(lb[4], lb[5], lb[6], lb[7]);
    #pragma unroll
    for (int off = 32; off > 0; off >>= 1) s += __shfl_down(s, off);
    if (lane == 0) sq[row] = s;
}

// ---------------------------------------------------------------------------
// Kernel 2: merged split-bf16 GEMM (Hi*Hi + Hi*Lo + Lo*Hi per K-tile),
// mfma_f32_32x32x16_bf16, fused loss, per-block reduction.
// 128x128 tile, 4 waves (2x2 of 64x64, each 2x2 frags of 32x32), BK=32.
// LDS: hi|lo interleaved 128B rows, 8-chunk XOR swizzle (chunk ^= row&7)
// -> 16-lane b128 read phases cover all 8 bank-quads twice = conflict-free.
// Double-buffered 64KB, counted vmcnt(8) (never 0 in-loop), raw s_barrier.
// ---------------------------------------------------------------------------
__global__ __launch_bounds__(256) void loss_kernel(
        const unsigned short* __restrict__ hi,
        const unsigned short* __restrict__ lo,
        const int*   __restrict__ seg,
        const float* __restrict__ sq,
        double*      __restrict__ partials) {
    __shared__ unsigned short smem[2 * BUFS];   // 64 KB

    int bid = blockIdx.x;
    int n = bid & 7;            // batch -> XCD round-robin
    int p = bid >> 3;           // 0..135
    int tj = 0;
    while (true) {
        int rl2 = NTILE - tj;
        if (p < rl2) break;
        p -= rl2;
        ++tj;
    }
    int tk = tj + p;
    int j0 = tj * BM, k0 = tk * BN;

    int t    = threadIdx.x;
    int w    = t >> 6;          // 0..3
    int lane = t & 63;
    int wr   = w >> 1, wc = w & 1;     // 64x64 quadrant
    int l31  = lane & 31;
    int hsel = lane >> 5;              // 0/1: k-halfslice of the frag

    const unsigned short* baseHi = hi + (size_t)n * L * DDIM;
    const unsigned short* baseLo = lo + (size_t)n * L * DDIM;

    // staging geometry: one gload_lds inst fills 8 rows x 128B = 1KB.
    // lane -> (row = lane>>3, phys chunk = lane&7). Logical chunk
    // lc = (lane&7) ^ (lane>>3) is lane-only (row mod 8 == lane>>3).
    int rl8 = lane >> 3;                 // 0..7 row within inst group
    int lc  = (lane & 7) ^ rl8;          // logical chunk 0..7
    const unsigned short* srcA0 = (lc < 4) ? baseHi : baseLo;  // per-lane
    const unsigned short* srcB0 = srcA0;
    int kco = (lc & 3) * 8;              // k-offset (shorts) within K-tile

    f32x16 acc[2][2];
    #pragma unroll
    for (int m = 0; m < 2; ++m)
        #pragma unroll
        for (int nn = 0; nn < 2; ++nn)
            #pragma unroll
            for (int r = 0; r < 16; ++r) acc[m][nn][r] = 0.0f;

    #define STAGE(kt, b)                                                      \
    {                                                                         \
        unsigned short* _dA = smem + (b) * BUFS;                              \
        unsigned short* _dB = _dA + TILE_SH;                                  \
        int _c0 = (kt) * BK + kco;                                            \
        _Pragma("unroll")                                                     \
        for (int q = 0; q < 4; ++q) {                                         \
            int inst = w * 4 + q;           /* 0..15 */                       \
            int r    = inst * 8 + rl8;      /* row 0..127 */                  \
            GLOAD_LDS16(srcA0 + (size_t)(j0 + r) * DDIM + _c0,                \
                        _dA + inst * 512);                                    \
            GLOAD_LDS16(srcB0 + (size_t)(k0 + r) * DDIM + _c0,                \
                        _dB + inst * 512);                                    \
        }                                                                     \
    }

    STAGE(0, 0);   // prologue

    #pragma unroll 2
    for (int kt = 0; kt < NKT; ++kt) {
        int cur = kt & 1;
        __builtin_amdgcn_s_barrier();          // all waves done reading buf[cur^1]
        if (kt + 1 < NKT) {
            STAGE(kt + 1, cur ^ 1);
            asm volatile("s_waitcnt vmcnt(8)" ::: "memory");  // tile kt resident
        } else {
            asm volatile("s_waitcnt vmcnt(0)" ::: "memory");
        }
        __builtin_amdgcn_s_barrier();          // tile kt visible to all waves

        const unsigned short* A = smem + cur * BUFS;
        const unsigned short* B = A + TILE_SH;

        #pragma unroll
        for (int ks = 0; ks < 2; ++ks) {       // two K=16 steps
            int kc = ks * 2 + hsel;            // logical hi-chunk 0..3
            bf16x8 ah[2], al[2], bh[2], bl[2];
            #pragma unroll
            for (int m = 0; m < 2; ++m) {
                int R = wr * 64 + m * 32 + l31;
                int s7 = R & 7;
                ah[m] = *(const bf16x8*)&A[R * 64 + ((kc       ^ s7) << 3)];
                al[m] = *(const bf16x8*)&A[R * 64 + (((4 + kc) ^ s7) << 3)];
            }
            #pragma unroll
            for (int nn = 0; nn < 2; ++nn) {
                int R = wc * 64 + nn * 32 + l31;
                int s7 = R & 7;
                bh[nn] = *(const bf16x8*)&B[R * 64 + ((kc       ^ s7) << 3)];
                bl[nn] = *(const bf16x8*)&B[R * 64 + (((4 + kc) ^ s7) << 3)];
            }
            __builtin_amdgcn_s_setprio(1);
            #pragma unroll
            for (int m = 0; m < 2; ++m)
                #pragma unroll
                for (int nn = 0; nn < 2; ++nn) {
                    acc[m][nn] = __builtin_amdgcn_mfma_f32_32x32x16_bf16(
                        ah[m], bh[nn], acc[m][nn], 0, 0, 0);
                    acc[m][nn] = __builtin_amdgcn_mfma_f32_32x32x16_bf16(
                        ah[m], bl[nn], acc[m][nn], 0, 0, 0);
                    acc[m][nn] = __builtin_amdgcn_mfma_f32_32x32x16_bf16(
                        al[m], bh[nn], acc[m][nn], 0, 0, 0);
                }
            __builtin_amdgcn_s_setprio(0);
        }
    }

    // ------------------- fused loss epilogue -------------------
    // 32x32 C/D layout: col = lane&31, row = (reg&3) + 8*(reg>>2) + 4*(lane>>5)
    const int*   segb = seg + n * L;
    const float* sqb  = sq + n * L;

    float sqk[2]; int sgk[2];
    #pragma unroll
    for (int nn = 0; nn < 2; ++nn) {
        int k = k0 + wc * 64 + nn * 32 + l31;
        sqk[nn] = sqb[k]; sgk[nn] = segb[k];
    }
    float sqj[2][16]; int sgj[2][16];
    #pragma unroll
    for (int m = 0; m < 2; ++m)
        #pragma unroll
        for (int r = 0; r < 16; ++r) {
            int j = j0 + wr * 64 + m * 32 + (r & 3) + 8 * (r >> 2) + 4 * hsel;
            sqj[m][r] = sqb[j]; sgj[m][r] = segb[j];
        }

    float lsum = 0.0f;
    #pragma unroll
    for (int m = 0; m < 2; ++m)
        #pragma unroll
        for (int nn = 0; nn < 2; ++nn)
            #pragma unroll
            for (int r = 0; r < 16; ++r) {
                float inner = acc[m][nn][r];
                float d2 = fmaxf(sqj[m][r] + sqk[nn] - 2.0f * inner, 0.0f);
                float v;
                if (sgj[m][r] == sgk[nn]) {
                    v = ALPHA * d2;
                } else {
                    float dist = sqrtf(d2);
                    float h = fmaxf(MARGIN - dist, 0.0f);
                    v = BETA * h * h;
                }
                lsum += v;
            }

    double wgt = (tj == tk) ? 1.0 : 2.0;
    __syncthreads();                       // done with LDS tiles
    double* red = (double*)smem;
    red[t] = (double)lsum * wgt;
    __syncthreads();
    #pragma unroll
    for (int s = 128; s > 0; s >>= 1) {
        if (t < s) red[t] += red[t + s];
        __syncthreads();
    }
    if (t == 0) partials[blockIdx.x] = red[0];
}

// ---------------------------------------------------------------------------
// Kernel 3: deterministic final reduction -> mean.
// ---------------------------------------------------------------------------
__global__ __launch_bounds__(256) void reduce_kernel(const double* __restrict__ partials,
                                                     float* __restrict__ out,
                                                     int nPart, double invCount) {
    __shared__ double red[256];
    int t = threadIdx.x;
    double s = 0.0;
    for (int i = t; i < nPart; i += 256) s += partials[i];
    red[t] = s;
    __syncthreads();
    #pragma unroll
    for (int k = 128; k > 0; k >>= 1) {
        if (t < k) red[t] += red[t + k];
        __syncthreads();
    }
    if (t == 0) out[0] = (float)(red[0] * invCount);
}

extern "C" void kernel_launch(void* const* d_in, const int* in_sizes, int n_in,
                              void* d_out, int out_size, void* d_ws, size_t ws_size,
                              hipStream_t stream) {
    const float* pred = (const float*)d_in[0];
    const int*   seg  = (const int*)d_in[1];
    float* out = (float*)d_out;

    const size_t HALF = (size_t)NBATCH * L * DDIM;
    unsigned short* hi = (unsigned short*)d_ws;
    unsigned short* lo = hi + HALF;
    float*  sq         = (float*)(lo + HALF);
    double* partials   = (double*)(sq + NBATCH * L);

    conv_kernel<<<NBATCH * L / 4, 256, 0, stream>>>(pred, hi, lo, sq);
    loss_kernel<<<TOTAL_BLOCKS, 256, 0, stream>>>(hi, lo, seg, sq, partials);
    reduce_kernel<<<1, 256, 0, stream>>>(partials, out, TOTAL_BLOCKS,
                                         1.0 / (double)((size_t)NBATCH * L * L));
}

// Round 7
// 71.010 us; speedup vs baseline: 1.4858x; 1.3568x over previous
//
#include <hip/hip_runtime.h>
#include <math.h>

#define L      2048
#define DDIM   512
#define NBATCH 8
#define BM     128
#define BN     128
#define BK     32
#define NKT    (DDIM / BK)               // 16 K-tiles
#define NTILE  (L / BM)                  // 16
#define NPAIR  (NTILE * (NTILE + 1) / 2) // 136
#define TOTAL_BLOCKS (NBATCH * NPAIR)    // 1088

#define ALPHA  0.1f
#define BETA   0.3f
#define MARGIN 2.0f

typedef _Float16 f16x8 __attribute__((ext_vector_type(8)));
typedef __attribute__((ext_vector_type(16))) float f32x16;

// per-buffer layout (f16 units): A tile 4096 (=[4 kc][128 rows][8]), B tile 4096
#define BUF_F16 8192      // 16 KB per buffer; 3 buffers = 48 KB

#define GLOAD_LDS16(g, l) __builtin_amdgcn_global_load_lds(              \
    (const __attribute__((address_space(1))) unsigned int*)(g),          \
    (__attribute__((address_space(3))) unsigned int*)(l), 16, 0, 0)

// ---------------------------------------------------------------------------
// Kernel 1: fp32 -> fp16 + per-row squared norms (exact fp32).
// ---------------------------------------------------------------------------
__global__ __launch_bounds__(256) void conv_kernel(const float* __restrict__ pred,
                                                   _Float16* __restrict__ h,
                                                   float* __restrict__ sq) {
    int w    = threadIdx.x >> 6;
    int lane = threadIdx.x & 63;
    int row  = blockIdx.x * 4 + w;
    const float* p = pred + (size_t)row * DDIM + lane * 8;
    float4 v0 = *(const float4*)(p);
    float4 v1 = *(const float4*)(p + 4);
    float vals[8] = {v0.x, v0.y, v0.z, v0.w, v1.x, v1.y, v1.z, v1.w};
    f16x8 hv;
    float s = 0.0f;
    #pragma unroll
    for (int i = 0; i < 8; ++i) {
        float x = vals[i];
        s = fmaf(x, x, s);
        hv[i] = (_Float16)x;
    }
    *(f16x8*)(h + (size_t)row * DDIM + lane * 8) = hv;
    #pragma unroll
    for (int off = 32; off > 0; off >>= 1) s += __shfl_down(s, off);
    if (lane == 0) sq[row] = s;
}

// ---------------------------------------------------------------------------
// Kernel 2: single-product fp16 GEMM (inner ~= h.h^T, fp32 accumulate) +
// fused loss + per-block reduction.
// 128x128 tile, 4 waves (2x2 of 64x64), mfma_f32_32x32x16_f16, BK=32.
// LDS k-major [kc][row][8]: frag ds_read_b128 is lane-consecutive ->
// bank-conflict-free with no swizzle. TRIPLE-buffered (48KB) -> 3 blocks/CU.
// Depth-2 prefetch, ONE s_barrier per kt, counted vmcnt(4) (never 0 mid-loop).
// ---------------------------------------------------------------------------
__global__ __launch_bounds__(256, 3) void loss_kernel(
        const _Float16* __restrict__ h,
        const int*   __restrict__ seg,
        const float* __restrict__ sq,
        double*      __restrict__ partials) {
    __shared__ _Float16 smem[3 * BUF_F16];   // 48 KB

    int bid = blockIdx.x;
    int n = bid & 7;            // batch -> XCD round-robin
    int p = bid >> 3;           // 0..135
    int tj = 0;
    while (true) {
        int rl2 = NTILE - tj;
        if (p < rl2) break;
        p -= rl2;
        ++tj;
    }
    int tk = tj + p;
    int j0 = tj * BM, k0 = tk * BN;

    int t    = threadIdx.x;
    int w    = t >> 6;          // 0..3
    int lane = t & 63;
    int wr   = w >> 1, wc = w & 1;     // 64x64 quadrant
    int l31  = lane & 31;
    int hsel = lane >> 5;              // 0/1: k-halfslice of the frag

    const _Float16* baseH = h + (size_t)n * L * DDIM;

    // staging: wave w covers kc pair {2(w&1), 2(w&1)+1} and row-group w>>1.
    // One gload_lds writes 64 consecutive rows of one kc block (1KB, linear).
    // Paired kc insts read the SAME 64B global lines -> guaranteed L1 reuse.
    int kc0  = (w & 1) * 2;
    int rg   = w >> 1;
    int srow = rg * 64 + lane;         // 0..127 (per-lane source row)

    f32x16 acc[2][2];
    #pragma unroll
    for (int m = 0; m < 2; ++m)
        #pragma unroll
        for (int nn = 0; nn < 2; ++nn)
            #pragma unroll
            for (int r = 0; r < 16; ++r) acc[m][nn][r] = 0.0f;

    #define STAGE(kt, b)                                                      \
    {                                                                         \
        _Float16* _A = smem + (b) * BUF_F16;                                  \
        _Float16* _B = _A + 4096;                                             \
        const _Float16* _sa = baseH + (size_t)(j0 + srow) * DDIM              \
                              + (kt) * BK + kc0 * 8;                          \
        const _Float16* _sb = baseH + (size_t)(k0 + srow) * DDIM              \
                              + (kt) * BK + kc0 * 8;                          \
        GLOAD_LDS16(_sa,     _A + kc0 * 1024 + rg * 512);                     \
        GLOAD_LDS16(_sa + 8, _A + (kc0 + 1) * 1024 + rg * 512);               \
        GLOAD_LDS16(_sb,     _B + kc0 * 1024 + rg * 512);                     \
        GLOAD_LDS16(_sb + 8, _B + (kc0 + 1) * 1024 + rg * 512);               \
    }

    STAGE(0, 0);
    STAGE(1, 1);

    #pragma unroll
    for (int kt = 0; kt < NKT; ++kt) {
        // tile kt (issued 2 iterations ago) must be complete; keep the 4
        // loads of tile kt+1 in flight (counted wait, never 0 mid-loop).
        if (kt + 2 < NKT) {
            asm volatile("s_waitcnt vmcnt(4)" ::: "memory");
        } else {
            asm volatile("s_waitcnt vmcnt(0)" ::: "memory");
        }
        __builtin_amdgcn_s_barrier();       // tile kt visible to all waves;
                                            // all waves done reading buf[(kt+2)%3]
        __builtin_amdgcn_sched_barrier(0);
        if (kt + 2 < NKT) STAGE(kt + 2, (kt + 2) % 3);

        const _Float16* A = smem + (kt % 3) * BUF_F16;
        const _Float16* B = A + 4096;

        #pragma unroll
        for (int ks = 0; ks < 2; ++ks) {    // two K=16 steps
            int kb = (2 * ks + hsel) * 1024;
            f16x8 af[2], bf[2];
            #pragma unroll
            for (int m = 0; m < 2; ++m)
                af[m] = *(const f16x8*)&A[kb + (wr * 64 + m * 32 + l31) * 8];
            #pragma unroll
            for (int nn = 0; nn < 2; ++nn)
                bf[nn] = *(const f16x8*)&B[kb + (wc * 64 + nn * 32 + l31) * 8];
            __builtin_amdgcn_s_setprio(1);
            #pragma unroll
            for (int m = 0; m < 2; ++m)
                #pragma unroll
                for (int nn = 0; nn < 2; ++nn)
                    acc[m][nn] = __builtin_amdgcn_mfma_f32_32x32x16_f16(
                        af[m], bf[nn], acc[m][nn], 0, 0, 0);
            __builtin_amdgcn_s_setprio(0);
        }
    }

    // ------------------- fused loss epilogue -------------------
    // 32x32 C/D layout: col = lane&31, row = (reg&3) + 8*(reg>>2) + 4*(lane>>5)
    const int*   segb = seg + n * L;
    const float* sqb  = sq + n * L;

    float lsum = 0.0f;
    #pragma unroll
    for (int nn = 0; nn < 2; ++nn) {
        int k = k0 + wc * 64 + nn * 32 + l31;
        float sqk = sqb[k];
        int   sgk = segb[k];
        #pragma unroll
        for (int m = 0; m < 2; ++m)
            #pragma unroll
            for (int r = 0; r < 16; ++r) {
                int j = j0 + wr * 64 + m * 32 + (r & 3) + 8 * (r >> 2) + 4 * hsel;
                float inner = acc[m][nn][r];
                float d2 = fmaxf(sqb[j] + sqk - 2.0f * inner, 0.0f);
                float v;
                if (segb[j] == sgk) {
                    v = ALPHA * d2;
                } else {
                    float dist = sqrtf(d2);
                    float hg = fmaxf(MARGIN - dist, 0.0f);
                    v = BETA * hg * hg;
                }
                lsum += v;
            }
    }

    double wgt = (tj == tk) ? 1.0 : 2.0;
    __syncthreads();                       // done with LDS tiles
    double* red = (double*)smem;
    red[t] = (double)lsum * wgt;
    __syncthreads();
    #pragma unroll
    for (int s = 128; s > 0; s >>= 1) {
        if (t < s) red[t] += red[t + s];
        __syncthreads();
    }
    if (t == 0) partials[blockIdx.x] = red[0];
}

// ---------------------------------------------------------------------------
// Kernel 3: deterministic final reduction -> mean.
// ---------------------------------------------------------------------------
__global__ __launch_bounds__(256) void reduce_kernel(const double* __restrict__ partials,
                                                     float* __restrict__ out,
                                                     int nPart, double invCount) {
    __shared__ double red[256];
    int t = threadIdx.x;
    double s = 0.0;
    for (int i = t; i < nPart; i += 256) s += partials[i];
    red[t] = s;
    __syncthreads();
    #pragma unroll
    for (int k = 128; k > 0; k >>= 1) {
        if (t < k) red[t] += red[t + k];
        __syncthreads();
    }
    if (t == 0) out[0] = (float)(red[0] * invCount);
}

extern "C" void kernel_launch(void* const* d_in, const int* in_sizes, int n_in,
                              void* d_out, int out_size, void* d_ws, size_t ws_size,
                              hipStream_t stream) {
    const float* pred = (const float*)d_in[0];
    const int*   seg  = (const int*)d_in[1];
    float* out = (float*)d_out;

    const size_t HALF = (size_t)NBATCH * L * DDIM;
    _Float16* h        = (_Float16*)d_ws;                    // 16.78 MB
    float*    sq       = (float*)(h + HALF);                 // 64 KB
    double*   partials = (double*)(sq + NBATCH * L);         // 8.7 KB

    conv_kernel<<<NBATCH * L / 4, 256, 0, stream>>>(pred, h, sq);
    loss_kernel<<<TOTAL_BLOCKS, 256, 0, stream>>>(h, seg, sq, partials);
    reduce_kernel<<<1, 256, 0, stream>>>(partials, out, TOTAL_BLOCKS,
                                         1.0 / (double)((size_t)NBATCH * L * L));
}

// Round 8
// 66.134 us; speedup vs baseline: 1.5954x; 1.0737x over previous
//
#include <hip/hip_runtime.h>
#include <math.h>

#define L      2048
#define DDIM   512
#define NBATCH 8
#define BM     128
#define BN     128
#define BK     64
#define NKT    (DDIM / BK)               // 8 K-tiles
#define NTILE  (L / BM)                  // 16
#define NPAIR  (NTILE * (NTILE + 1) / 2) // 136
#define TOTAL_BLOCKS (NBATCH * NPAIR)    // 1088

#define ALPHA  0.1f
#define BETA   0.3f
#define MARGIN 2.0f

typedef _Float16 f16x8 __attribute__((ext_vector_type(8)));
typedef __attribute__((ext_vector_type(16))) float f32x16;

// Buffer: A tile [128 rows x 128B] then B tile [128 rows x 128B].
// Row = 8 chunks of 8 f16 (16B); physical chunk = logical ^ (row & 7).
#define TILE_SH 8192       // f16 per tile (16 KB)
#define BUFSZ   16384      // f16 per buffer (32 KB); x2 buffers = 64 KB

#define GLOAD_LDS16(g, l) __builtin_amdgcn_global_load_lds(              \
    (const __attribute__((address_space(1))) unsigned int*)(g),          \
    (__attribute__((address_space(3))) unsigned int*)(l), 16, 0, 0)

// ---------------------------------------------------------------------------
// Kernel 1: fp32 -> fp16 + per-row squared norms (exact fp32).
// ---------------------------------------------------------------------------
__global__ __launch_bounds__(256) void conv_kernel(const float* __restrict__ pred,
                                                   _Float16* __restrict__ h,
                                                   float* __restrict__ sq) {
    int w    = threadIdx.x >> 6;
    int lane = threadIdx.x & 63;
    int row  = blockIdx.x * 4 + w;
    const float* p = pred + (size_t)row * DDIM + lane * 8;
    float4 v0 = *(const float4*)(p);
    float4 v1 = *(const float4*)(p + 4);
    float vals[8] = {v0.x, v0.y, v0.z, v0.w, v1.x, v1.y, v1.z, v1.w};
    f16x8 hv;
    float s = 0.0f;
    #pragma unroll
    for (int i = 0; i < 8; ++i) {
        float x = vals[i];
        s = fmaf(x, x, s);
        hv[i] = (_Float16)x;
    }
    *(f16x8*)(h + (size_t)row * DDIM + lane * 8) = hv;
    #pragma unroll
    for (int off = 32; off > 0; off >>= 1) s += __shfl_down(s, off);
    if (lane == 0) sq[row] = s;
}

// ---------------------------------------------------------------------------
// Kernel 2: fp16 Gram GEMM + fused loss + per-block reduction.
// 128x128 tile, 4 waves (2x2 of 64x64), mfma_f32_32x32x16_f16, BK=64.
// 8 K-tiles; 16 MFMA + 16 ds_read_b128 per wave per tile; ONE barrier/tile.
// Double-buffered 64 KB -> 2 blocks/CU. STAGE(kt+1) issued at TOP of tile kt
// (full-tile latency cover), vmcnt(0)+barrier at tile end.
// Staging: instr = 8 rows x 128B, 8 lanes/row, XOR chunk-swizzle on source;
// frag ds_read uses same XOR -> conflict-free (all 8 chunks per 8 lanes).
// ---------------------------------------------------------------------------
__global__ __launch_bounds__(256, 2) void loss_kernel(
        const _Float16* __restrict__ h,
        const int*   __restrict__ seg,
        const float* __restrict__ sq,
        double*      __restrict__ partials) {
    __shared__ _Float16 smem[2 * BUFSZ];   // 64 KB

    int bid = blockIdx.x;
    int n = bid & 7;            // batch -> XCD round-robin
    int p = bid >> 3;           // 0..135
    int tj = 0;
    while (true) {
        int rl2 = NTILE - tj;
        if (p < rl2) break;
        p -= rl2;
        ++tj;
    }
    int tk = tj + p;
    int j0 = tj * BM, k0 = tk * BN;

    int t    = threadIdx.x;
    int w    = t >> 6;          // 0..3
    int lane = t & 63;
    int wr   = w >> 1, wc = w & 1;     // 64x64 quadrant
    int l31  = lane & 31;
    int hsel = lane >> 5;              // 0/1: k-halfslice of the frag

    const _Float16* baseH = h + (size_t)n * L * DDIM;

    // staging: instr i covers tile rows i*8..i*8+7.
    // lane -> row-in-group rl8 = lane>>3, physical chunk pc = lane&7.
    // logical chunk lc = pc ^ rl8 (row&7 == rl8). Source is row-major:
    // 8 lanes per row read the row's 8 chunks (permuted) = 2 cache lines.
    int rl8 = lane >> 3;
    int lc  = (lane & 7) ^ rl8;
    const _Float16* srcAbase = baseH + (size_t)(j0 + rl8) * DDIM + lc * 8;
    const _Float16* srcBbase = baseH + (size_t)(k0 + rl8) * DDIM + lc * 8;

    f32x16 acc[2][2];
    #pragma unroll
    for (int m = 0; m < 2; ++m)
        #pragma unroll
        for (int nn = 0; nn < 2; ++nn)
            #pragma unroll
            for (int r = 0; r < 16; ++r) acc[m][nn][r] = 0.0f;

    // wave w stages A-instrs {4w..4w+3} and B-instrs {4w..4w+3}
    #define STAGE(kt, b)                                                      \
    {                                                                         \
        _Float16* _A = smem + (b) * BUFSZ;                                    \
        _Float16* _B = _A + TILE_SH;                                          \
        _Pragma("unroll")                                                     \
        for (int q = 0; q < 4; ++q) {                                         \
            int inst = w * 4 + q;                                             \
            GLOAD_LDS16(srcAbase + (size_t)(inst * 8) * DDIM + (kt) * BK,     \
                        _A + inst * 512);                                     \
            GLOAD_LDS16(srcBbase + (size_t)(inst * 8) * DDIM + (kt) * BK,     \
                        _B + inst * 512);                                     \
        }                                                                     \
    }

    STAGE(0, 0);
    asm volatile("s_waitcnt vmcnt(0)" ::: "memory");
    __builtin_amdgcn_s_barrier();

    #pragma unroll
    for (int kt = 0; kt < NKT; ++kt) {
        const int cur = kt & 1;
        if (kt + 1 < NKT) STAGE(kt + 1, cur ^ 1);   // issue early: full-tile cover

        const _Float16* A = smem + cur * BUFSZ;
        const _Float16* B = A + TILE_SH;

        #pragma unroll
        for (int ks = 0; ks < 4; ++ks) {            // four K=16 steps
            int c = ks * 2 + hsel;                  // logical chunk 0..7
            f16x8 af[2], bf[2];
            #pragma unroll
            for (int m = 0; m < 2; ++m) {
                int R = wr * 64 + m * 32 + l31;
                af[m] = *(const f16x8*)&A[R * 64 + ((c ^ (R & 7)) << 3)];
            }
            #pragma unroll
            for (int nn = 0; nn < 2; ++nn) {
                int R = wc * 64 + nn * 32 + l31;
                bf[nn] = *(const f16x8*)&B[R * 64 + ((c ^ (R & 7)) << 3)];
            }
            __builtin_amdgcn_s_setprio(1);
            #pragma unroll
            for (int m = 0; m < 2; ++m)
                #pragma unroll
                for (int nn = 0; nn < 2; ++nn)
                    acc[m][nn] = __builtin_amdgcn_mfma_f32_32x32x16_f16(
                        af[m], bf[nn], acc[m][nn], 0, 0, 0);
            __builtin_amdgcn_s_setprio(0);
        }

        // own STAGE(kt+1) writes drained (had a full tile of cover), then
        // block-wide visibility. Single barrier per K-tile.
        asm volatile("s_waitcnt vmcnt(0)" ::: "memory");
        __builtin_amdgcn_s_barrier();
    }

    // ------------------- fused loss epilogue -------------------
    // 32x32 C/D layout: col = lane&31, row = (reg&3) + 8*(reg>>2) + 4*(lane>>5)
    const int*   segb = seg + n * L;
    const float* sqb  = sq + n * L;

    float lsum = 0.0f;
    #pragma unroll
    for (int nn = 0; nn < 2; ++nn) {
        int k = k0 + wc * 64 + nn * 32 + l31;
        float sqk = sqb[k];
        int   sgk = segb[k];
        #pragma unroll
        for (int m = 0; m < 2; ++m)
            #pragma unroll
            for (int r = 0; r < 16; ++r) {
                int j = j0 + wr * 64 + m * 32 + (r & 3) + 8 * (r >> 2) + 4 * hsel;
                float inner = acc[m][nn][r];
                float d2 = fmaxf(sqb[j] + sqk - 2.0f * inner, 0.0f);
                float v;
                if (segb[j] == sgk) {
                    v = ALPHA * d2;
                } else {
                    float dist = sqrtf(d2);
                    float hg = fmaxf(MARGIN - dist, 0.0f);
                    v = BETA * hg * hg;
                }
                lsum += v;
            }
    }

    double wgt = (tj == tk) ? 1.0 : 2.0;
    __syncthreads();                       // done with LDS tiles
    double* red = (double*)smem;
    red[t] = (double)lsum * wgt;
    __syncthreads();
    #pragma unroll
    for (int s = 128; s > 0; s >>= 1) {
        if (t < s) red[t] += red[t + s];
        __syncthreads();
    }
    if (t == 0) partials[blockIdx.x] = red[0];
}

// ---------------------------------------------------------------------------
// Kernel 3: deterministic final reduction -> mean.
// ---------------------------------------------------------------------------
__global__ __launch_bounds__(256) void reduce_kernel(const double* __restrict__ partials,
                                                     float* __restrict__ out,
                                                     int nPart, double invCount) {
    __shared__ double red[256];
    int t = threadIdx.x;
    double s = 0.0;
    for (int i = t; i < nPart; i += 256) s += partials[i];
    red[t] = s;
    __syncthreads();
    #pragma unroll
    for (int k = 128; k > 0; k >>= 1) {
        if (t < k) red[t] += red[t + k];
        __syncthreads();
    }
    if (t == 0) out[0] = (float)(red[0] * invCount);
}

extern "C" void kernel_launch(void* const* d_in, const int* in_sizes, int n_in,
                              void* d_out, int out_size, void* d_ws, size_t ws_size,
                              hipStream_t stream) {
    const float* pred = (const float*)d_in[0];
    const int*   seg  = (const int*)d_in[1];
    float* out = (float*)d_out;

    const size_t HALF = (size_t)NBATCH * L * DDIM;
    _Float16* h        = (_Float16*)d_ws;                    // 16.78 MB
    float*    sq       = (float*)(h + HALF);                 // 64 KB
    double*   partials = (double*)(sq + NBATCH * L);         // 8.7 KB

    conv_kernel<<<NBATCH * L / 4, 256, 0, stream>>>(pred, h, sq);
    loss_kernel<<<TOTAL_BLOCKS, 256, 0, stream>>>(h, seg, sq, partials);
    reduce_kernel<<<1, 256, 0, stream>>>(partials, out, TOTAL_BLOCKS,
                                         1.0 / (double)((size_t)NBATCH * L * L));
}